// Round 2
// baseline (1500.028 us; speedup 1.0000x reference)
//
#include <hip/hip_runtime.h>
#include <hip/hip_bf16.h>

// DistanceEncoder: B=2, N=512, HID=OUT=128. All-pairs distances -> 3 SiLU-MLP
// layers (width 128) -> mean over source nodes -> final projection.
// Inputs/outputs: fp32 per reference (device-side sniff handles bf16 too).
// Internal compute: bf16 MFMA with split-weight (hi+lo) for ~fp32 weight
// precision; fp32 accumulation; activations bf16 (j-varying error washes in
// the mean over 512).

typedef __attribute__((ext_vector_type(8))) short short8;
typedef __attribute__((ext_vector_type(4))) float floatx4;

#define LDP 136   // 128 + 8 bf16 pad: rows 16B-aligned, conflict-free b128

// ws byte offsets
#define WS_FLAG   0          // int: 1 = fp32 inputs, 0 = bf16 inputs
#define WS_WT     16         // 5 matrices x [n(128)][hi(128)|lo(128)] bf16 = 327680 B
#define WS_WOT    327696     // Wo^T fp32 [o(128)][k(128)] = 65536 B
#define WS_PARAMS 393232     // 8 x 128 fp32: w10,b10,b20,b11,b21,b12,b22,bo
#define WS_XF     397328     // x fp32, 2048 floats
#define WS_NEED   405520

__device__ __forceinline__ float bf2f(ushort u) {
  union { unsigned int i; float f; } v; v.i = ((unsigned int)u) << 16; return v.f;
}
__device__ __forceinline__ ushort f2bf(float f) {
  union { float f; unsigned int i; } v; v.f = f;
  return (ushort)((v.i + 0x7FFFu + ((v.i >> 16) & 1u)) >> 16);  // RNE
}
__device__ __forceinline__ float silu_f(float a) {
  float e = __builtin_amdgcn_exp2f(-1.44269504089f * a);   // exp(-a)
  return a * __builtin_amdgcn_rcpf(1.0f + e);              // a * sigmoid(a)
}
__device__ __forceinline__ float dload(const void* p, int idx, int isf32) {
  return isf32 ? ((const float*)p)[idx] : bf2f(((const ushort*)p)[idx]);
}

// ---- kernel 0: decide input dtype from x's bit patterns --------------------
// fp32 data read as ushorts: low halves are random mantissa bits -> many
// insane bf16 exponents. bf16 N(0,1) data: none.
__global__ void sniff_dtype(const ushort* __restrict__ x, int* __restrict__ flag) {
  __shared__ int cnt;
  if (threadIdx.x == 0) cnt = 0;
  __syncthreads();
  int c = 0;
  for (int i = threadIdx.x; i < 256; i += 64) {
    const int e = (x[i] >> 7) & 0xFF;
    if (e >= 0xC0 || (e >= 1 && e <= 0x40)) ++c;   // |v|>=2^65 or 0<|v|<2^-63
  }
  atomicAdd(&cnt, c);
  __syncthreads();
  if (threadIdx.x == 0) *flag = (cnt > 8) ? 1 : 0;
}

// ---- kernel 1: build canonical ws image ------------------------------------
__global__ __launch_bounds__(128) void prep_kernel(
    const void* __restrict__ x,
    const void* __restrict__ w10, const void* __restrict__ b10,
    const void* __restrict__ W20, const void* __restrict__ b20,
    const void* __restrict__ W11, const void* __restrict__ b11,
    const void* __restrict__ W21, const void* __restrict__ b21,
    const void* __restrict__ W12, const void* __restrict__ b12,
    const void* __restrict__ W22, const void* __restrict__ b22,
    const void* __restrict__ Wo,  const void* __restrict__ bo,
    char* __restrict__ ws)
{
  const int isf32 = *(const int*)(ws + WS_FLAG);
  const int blk = blockIdx.x;
  const int t = threadIdx.x;
  ushort* wt     = (ushort*)(ws + WS_WT);
  float*  wot    = (float*)(ws + WS_WOT);
  float*  params = (float*)(ws + WS_PARAMS);
  float*  xf     = (float*)(ws + WS_XF);

  if (blk < 640) {                      // transpose + hi/lo split, 5 matrices
    const int m = blk >> 7, n = blk & 127;
    const void* src = (m == 0) ? W20 : (m == 1) ? W11 : (m == 2) ? W21
                    : (m == 3) ? W12 : W22;
    const float w = dload(src, t * 128 + n, isf32);   // W[k=t][n]
    const ushort hi = f2bf(w);
    const float lo = w - bf2f(hi);
    wt[m * 32768 + n * 256 + t]       = hi;
    wt[m * 32768 + n * 256 + 128 + t] = f2bf(lo);
  } else if (blk < 768) {               // Wo^T fp32
    const int o = blk - 640;
    wot[o * 128 + t] = dload(Wo, t * 128 + o, isf32);
  } else {                              // params + x
    const void* vecs[8] = {w10, b10, b20, b11, b21, b12, b22, bo};
    for (int v = 0; v < 8; ++v) params[v * 128 + t] = dload(vecs[v], t, isf32);
    for (int i = t; i < 2048; i += 128) xf[i] = dload(x, i, isf32);
  }
}

// ---- MFMA tile helpers -----------------------------------------------------
// Verified gfx950 16x16x32 bf16 layouts:
//   A: lane l holds A[m = l&15][k = (l>>4)*8 + t]          (m120)
//   B: lane l holds B[k = (l>>4)*8 + t][n = l&15]
//   C/D: lane l, reg r -> row (l>>4)*4 + r, col l&15       (m89)
// wtm layout: [n][hi 0..127 | lo 0..127] bf16, k contiguous.
template<bool ACT>
__device__ __forceinline__ void gemm_tile(
    const ushort* sIn, ushort* sOut, const ushort* __restrict__ wtm,
    const float* bias, int wave, int ln, int quad)
{
  const int row0 = wave * 32;
  short8 aF[2][4];
#pragma unroll
  for (int mt = 0; mt < 2; ++mt)
#pragma unroll
    for (int kk = 0; kk < 4; ++kk)
      aF[mt][kk] = *(const short8*)(sIn + (row0 + mt * 16 + ln) * LDP + kk * 32 + quad * 8);

#pragma unroll
  for (int nt = 0; nt < 8; ++nt) {
    const int col = nt * 16 + ln;
    floatx4 acc0 = {0.f, 0.f, 0.f, 0.f};
    floatx4 acc1 = {0.f, 0.f, 0.f, 0.f};
#pragma unroll
    for (int kk = 0; kk < 4; ++kk) {
      const ushort* bp = wtm + col * 256 + kk * 32 + quad * 8;
      const short8 bH = *(const short8*)bp;
      const short8 bL = *(const short8*)(bp + 128);
      acc0 = __builtin_amdgcn_mfma_f32_16x16x32_bf16(aF[0][kk], bH, acc0, 0, 0, 0);
      acc0 = __builtin_amdgcn_mfma_f32_16x16x32_bf16(aF[0][kk], bL, acc0, 0, 0, 0);
      acc1 = __builtin_amdgcn_mfma_f32_16x16x32_bf16(aF[1][kk], bH, acc1, 0, 0, 0);
      acc1 = __builtin_amdgcn_mfma_f32_16x16x32_bf16(aF[1][kk], bL, acc1, 0, 0, 0);
    }
    const float bv = bias[col];
#pragma unroll
    for (int r = 0; r < 4; ++r) {
      float v0 = acc0[r] + bv;
      float v1 = acc1[r] + bv;
      if (ACT) { v0 = silu_f(v0); v1 = silu_f(v1); }
      sOut[(row0 + quad * 4 + r) * LDP + col] = f2bf(v0);
      sOut[(row0 + 16 + quad * 4 + r) * LDP + col] = f2bf(v1);
    }
  }
}

__device__ __forceinline__ void gemm_reduce_tile(
    const ushort* sIn, float* colsum, const ushort* __restrict__ wtm,
    const float* bias, int wave, int ln, int quad)
{
  const int row0 = wave * 32;
  short8 aF[2][4];
#pragma unroll
  for (int mt = 0; mt < 2; ++mt)
#pragma unroll
    for (int kk = 0; kk < 4; ++kk)
      aF[mt][kk] = *(const short8*)(sIn + (row0 + mt * 16 + ln) * LDP + kk * 32 + quad * 8);

#pragma unroll
  for (int nt = 0; nt < 8; ++nt) {
    const int col = nt * 16 + ln;
    floatx4 acc0 = {0.f, 0.f, 0.f, 0.f};
    floatx4 acc1 = {0.f, 0.f, 0.f, 0.f};
#pragma unroll
    for (int kk = 0; kk < 4; ++kk) {
      const ushort* bp = wtm + col * 256 + kk * 32 + quad * 8;
      const short8 bH = *(const short8*)bp;
      const short8 bL = *(const short8*)(bp + 128);
      acc0 = __builtin_amdgcn_mfma_f32_16x16x32_bf16(aF[0][kk], bH, acc0, 0, 0, 0);
      acc0 = __builtin_amdgcn_mfma_f32_16x16x32_bf16(aF[0][kk], bL, acc0, 0, 0, 0);
      acc1 = __builtin_amdgcn_mfma_f32_16x16x32_bf16(aF[1][kk], bH, acc1, 0, 0, 0);
      acc1 = __builtin_amdgcn_mfma_f32_16x16x32_bf16(aF[1][kk], bL, acc1, 0, 0, 0);
    }
    const float p = acc0[0] + acc0[1] + acc0[2] + acc0[3]
                  + acc1[0] + acc1[1] + acc1[2] + acc1[3] + 8.0f * bias[col];
    atomicAdd(&colsum[col], p);   // 8 of the wave's 32 rows, fixed col
  }
}

// ---- kernel 2: the fused encoder ------------------------------------------
__global__ __launch_bounds__(256, 2) void fused_ws(
    const char* __restrict__ ws, void* __restrict__ out)
{
  __shared__ __align__(16) ushort sA[128 * LDP];
  __shared__ __align__(16) ushort sB[128 * LDP];
  __shared__ float sw10[128], sb10[128];
  __shared__ float sbias[5][128];
  __shared__ float colsum[128];
  __shared__ float dists[128];

  const int tid  = threadIdx.x;
  const int wave = tid >> 6;
  const int ln   = tid & 15;
  const int quad = (tid & 63) >> 4;

  const int b = blockIdx.x >> 9;
  const int i = blockIdx.x & 511;

  const int isf32      = *(const int*)(ws + WS_FLAG);
  const ushort* wt     = (const ushort*)(ws + WS_WT);
  const float*  wot    = (const float*)(ws + WS_WOT);
  const float*  params = (const float*)(ws + WS_PARAMS);
  const float*  xf     = (const float*)(ws + WS_XF);

  if (tid < 128) {
    sw10[tid]     = params[0 * 128 + tid];
    sb10[tid]     = params[1 * 128 + tid];
    sbias[0][tid] = params[2 * 128 + tid];
    sbias[1][tid] = params[3 * 128 + tid];
    sbias[2][tid] = params[4 * 128 + tid];
    sbias[3][tid] = params[5 * 128 + tid];
    sbias[4][tid] = params[6 * 128 + tid];
    colsum[tid]   = 0.f;
  }
  const float xi0 = xf[(b * 512 + i) * 2 + 0];
  const float xi1 = xf[(b * 512 + i) * 2 + 1];
  __syncthreads();

  for (int chunk = 0; chunk < 4; ++chunk) {
    if (tid < 128) {
      const int j = chunk * 128 + tid;
      const float dx = xi0 - xf[(b * 512 + j) * 2 + 0];
      const float dy = xi1 - xf[(b * 512 + j) * 2 + 1];
      dists[tid] = sqrtf(dx * dx + dy * dy);
    }
    __syncthreads();

    // layer 0: a0[jj][c] = silu(d[jj]*w10[c] + b10[c]) -> sA (bf16)
    for (int e = tid; e < 128 * 128; e += 256) {
      const int jj = e >> 7, c = e & 127;
      sA[jj * LDP + c] = f2bf(silu_f(dists[jj] * sw10[c] + sb10[c]));
    }
    __syncthreads();

    gemm_tile<false>(sA, sB, wt + 0 * 32768, sbias[0], wave, ln, quad); // h1
    __syncthreads();
    gemm_tile<true >(sB, sA, wt + 1 * 32768, sbias[1], wave, ln, quad); // a1
    __syncthreads();
    gemm_tile<false>(sA, sB, wt + 2 * 32768, sbias[2], wave, ln, quad); // h2
    __syncthreads();
    gemm_tile<true >(sB, sA, wt + 3 * 32768, sbias[3], wave, ln, quad); // a2
    __syncthreads();
    gemm_reduce_tile(sA, colsum, wt + 4 * 32768, sbias[4], wave, ln, quad);
    // next chunk's post-dists barrier orders these sA reads vs. next writes
  }
  __syncthreads();

  // out[b,i,o] = (colsum/512) . Wo[:,o] + bo[o]   (all fp32)
  if (tid < 128) {
    const int o = tid;
    float s = params[7 * 128 + o];                  // bo
    const float inv = 1.0f / 512.0f;
#pragma unroll 4
    for (int k = 0; k < 128; ++k)
      s += (colsum[k] * inv) * wot[o * 128 + k];
    const int idx = (b * 512 + i) * 128 + o;
    if (isf32) ((float*)out)[idx] = s;
    else       ((ushort*)out)[idx] = f2bf(s);
  }
}

// ---- fallback (ws too small): fp32-direct, gathered weights ---------------
template<bool ACT>
__device__ __forceinline__ void gemm_tile_g(
    const ushort* sIn, ushort* sOut, const float* __restrict__ W,
    const float* bias, int wave, int ln, int quad)
{
  const int row0 = wave * 32;
  short8 aF[2][4];
#pragma unroll
  for (int mt = 0; mt < 2; ++mt)
#pragma unroll
    for (int kk = 0; kk < 4; ++kk)
      aF[mt][kk] = *(const short8*)(sIn + (row0 + mt * 16 + ln) * LDP + kk * 32 + quad * 8);
#pragma unroll
  for (int nt = 0; nt < 8; ++nt) {
    const int col = nt * 16 + ln;
    floatx4 acc0 = {0.f, 0.f, 0.f, 0.f};
    floatx4 acc1 = {0.f, 0.f, 0.f, 0.f};
#pragma unroll
    for (int kk = 0; kk < 4; ++kk) {
      short8 bF;
#pragma unroll
      for (int t = 0; t < 8; ++t)
        bF[t] = (short)f2bf(W[(kk * 32 + quad * 8 + t) * 128 + col]);
      acc0 = __builtin_amdgcn_mfma_f32_16x16x32_bf16(aF[0][kk], bF, acc0, 0, 0, 0);
      acc1 = __builtin_amdgcn_mfma_f32_16x16x32_bf16(aF[1][kk], bF, acc1, 0, 0, 0);
    }
    const float bv = bias[col];
#pragma unroll
    for (int r = 0; r < 4; ++r) {
      float v0 = acc0[r] + bv;
      float v1 = acc1[r] + bv;
      if (ACT) { v0 = silu_f(v0); v1 = silu_f(v1); }
      sOut[(row0 + quad * 4 + r) * LDP + col] = f2bf(v0);
      sOut[(row0 + 16 + quad * 4 + r) * LDP + col] = f2bf(v1);
    }
  }
}

__global__ __launch_bounds__(256, 2) void fused_direct(
    const float* __restrict__ x,
    const float* __restrict__ w10, const float* __restrict__ b10,
    const float* __restrict__ W20, const float* __restrict__ b20,
    const float* __restrict__ W11, const float* __restrict__ b11,
    const float* __restrict__ W21, const float* __restrict__ b21,
    const float* __restrict__ W12, const float* __restrict__ b12,
    const float* __restrict__ W22, const float* __restrict__ b22,
    const float* __restrict__ Wo,  const float* __restrict__ bo,
    float* __restrict__ out)
{
  __shared__ __align__(16) ushort sA[128 * LDP];
  __shared__ __align__(16) ushort sB[128 * LDP];
  __shared__ float sw10[128], sb10[128];
  __shared__ float sbias[5][128];
  __shared__ float colsum[128];
  __shared__ float dists[128];

  const int tid  = threadIdx.x;
  const int wave = tid >> 6;
  const int ln   = tid & 15;
  const int quad = (tid & 63) >> 4;
  const int b = blockIdx.x >> 9;
  const int i = blockIdx.x & 511;

  if (tid < 128) {
    sw10[tid] = w10[tid]; sb10[tid] = b10[tid];
    sbias[0][tid] = b20[tid]; sbias[1][tid] = b11[tid];
    sbias[2][tid] = b21[tid]; sbias[3][tid] = b12[tid];
    sbias[4][tid] = b22[tid]; colsum[tid] = 0.f;
  }
  const float xi0 = x[(b * 512 + i) * 2 + 0];
  const float xi1 = x[(b * 512 + i) * 2 + 1];
  __syncthreads();

  for (int chunk = 0; chunk < 4; ++chunk) {
    if (tid < 128) {
      const int j = chunk * 128 + tid;
      const float dx = xi0 - x[(b * 512 + j) * 2 + 0];
      const float dy = xi1 - x[(b * 512 + j) * 2 + 1];
      dists[tid] = sqrtf(dx * dx + dy * dy);
    }
    __syncthreads();
    for (int e = tid; e < 128 * 128; e += 256) {
      const int jj = e >> 7, c = e & 127;
      sA[jj * LDP + c] = f2bf(silu_f(dists[jj] * sw10[c] + sb10[c]));
    }
    __syncthreads();
    gemm_tile_g<false>(sA, sB, W20, sbias[0], wave, ln, quad);
    __syncthreads();
    gemm_tile_g<true >(sB, sA, W11, sbias[1], wave, ln, quad);
    __syncthreads();
    gemm_tile_g<false>(sA, sB, W21, sbias[2], wave, ln, quad);
    __syncthreads();
    gemm_tile_g<true >(sB, sA, W12, sbias[3], wave, ln, quad);
    __syncthreads();
    // last layer: compute h3 into sB, then reduce scalar (simple, rare path)
    gemm_tile_g<false>(sB, sB, W22, sbias[4], wave, ln, quad);
    __syncthreads();
    if (tid < 128) {
      float s = 0.f;
      for (int jj = 0; jj < 128; ++jj) s += bf2f(sB[jj * LDP + tid]);
      atomicAdd(&colsum[tid], s);
    }
    __syncthreads();
  }

  if (tid < 128) {
    const int o = tid;
    float s = bo[o];
    const float inv = 1.0f / 512.0f;
    for (int k = 0; k < 128; ++k) s += (colsum[k] * inv) * Wo[k * 128 + o];
    out[(b * 512 + i) * 128 + o] = s;
  }
}

extern "C" void kernel_launch(void* const* d_in, const int* in_sizes, int n_in,
                              void* d_out, int out_size, void* d_ws, size_t ws_size,
                              hipStream_t stream) {
  (void)in_sizes; (void)n_in; (void)out_size;
  if (ws_size >= (size_t)WS_NEED) {
    sniff_dtype<<<1, 64, 0, stream>>>((const ushort*)d_in[0], (int*)d_ws);
    prep_kernel<<<769, 128, 0, stream>>>(
        d_in[0], d_in[1], d_in[2], d_in[3], d_in[4], d_in[5], d_in[6],
        d_in[7], d_in[8], d_in[9], d_in[10], d_in[11], d_in[12], d_in[13],
        d_in[14], (char*)d_ws);
    fused_ws<<<1024, 256, 0, stream>>>((const char*)d_ws, d_out);
  } else {
    fused_direct<<<1024, 256, 0, stream>>>(
        (const float*)d_in[0], (const float*)d_in[1], (const float*)d_in[2],
        (const float*)d_in[3], (const float*)d_in[4], (const float*)d_in[5],
        (const float*)d_in[6], (const float*)d_in[7], (const float*)d_in[8],
        (const float*)d_in[9], (const float*)d_in[10], (const float*)d_in[11],
        (const float*)d_in[12], (const float*)d_in[13], (const float*)d_in[14],
        (float*)d_out);
  }
}

// Round 3
// 210.390 us; speedup vs baseline: 7.1298x; 7.1298x over previous
//
#include <hip/hip_runtime.h>
#include <hip/hip_bf16.h>
#include <hip/hip_fp16.h>

// DistanceEncoder: B=2, N=512, HID=OUT=128. All-pairs distances -> 3 SiLU-MLP
// layers -> mean over j -> projection.
// Structure (R2): weights f16, VGPR-resident per wave (col-split: wave w owns
// output cols 32w..32w+31 of every layer). Activations f16 in LDS ping-pong.
// MFMA 16x16x32 f16, fp32 accum. fp32 colsum + fp32 epilogue.

typedef _Float16 half8 __attribute__((ext_vector_type(8)));
typedef __attribute__((ext_vector_type(4))) short short4v;
typedef __attribute__((ext_vector_type(4))) float floatx4;

#define LDP 136   // ushorts; rows 272 B -> 16B-aligned, ds_read_b128-friendly

// ws byte offsets
#define WS_FLAG   0          // int: 1 = fp32 inputs, 0 = bf16 inputs
#define WS_WT2    16         // f16 frags: [L(5)][w(4)][n(2)][kk(4)][lane(64)][8] = 163840 B
#define WS_WOT    163856     // Wo^T fp32 [o(128)][k(128)] = 65536 B
#define WS_PARAMS 229392     // 8 x 128 fp32: w10,b10,b20,b11,b21,b12,b22,bo
#define WS_XF     233488     // x fp32, 2048 floats
#define WS_NEED   241680

__device__ __forceinline__ float bf2f(ushort u) {
  union { unsigned int i; float f; } v; v.i = ((unsigned int)u) << 16; return v.f;
}
__device__ __forceinline__ ushort f2bf(float f) {
  union { float f; unsigned int i; } v; v.f = f;
  return (ushort)((v.i + 0x7FFFu + ((v.i >> 16) & 1u)) >> 16);
}
__device__ __forceinline__ ushort f2h_bits(float f) {
  union { _Float16 h; ushort u; } v; v.h = (_Float16)f; return v.u;
}
__device__ __forceinline__ float silu_f(float a) {
  float e = __builtin_amdgcn_exp2f(-1.44269504089f * a);   // exp(-a)
  return a * __builtin_amdgcn_rcpf(1.0f + e);
}
__device__ __forceinline__ float dload(const void* p, int idx, int isf32) {
  return isf32 ? ((const float*)p)[idx] : bf2f(((const ushort*)p)[idx]);
}

// ---- kernel 0: input dtype sniff ------------------------------------------
__global__ void sniff_dtype(const ushort* __restrict__ x, int* __restrict__ flag) {
  __shared__ int cnt;
  if (threadIdx.x == 0) cnt = 0;
  __syncthreads();
  int c = 0;
  for (int i = threadIdx.x; i < 256; i += 64) {
    const int e = (x[i] >> 7) & 0xFF;
    if (e >= 0xC0 || (e >= 1 && e <= 0x40)) ++c;
  }
  atomicAdd(&cnt, c);
  __syncthreads();
  if (threadIdx.x == 0) *flag = (cnt > 8) ? 1 : 0;
}

// ---- kernel 1: build ws image ---------------------------------------------
// Weight fragments stored in EXACT lane order for coalesced block-start loads:
// elem(L,w,n,kk,lane,t) at ((((L*4+w)*2+n)*4+kk)*64+lane)*8+t, where
// col = w*32+n*16+(lane&15), k = kk*32+(lane>>4)*8+t, value = f16(W_L[k][col]).
__global__ __launch_bounds__(256) void prep_kernel(
    const void* __restrict__ x,
    const void* __restrict__ w10, const void* __restrict__ b10,
    const void* __restrict__ W20, const void* __restrict__ b20,
    const void* __restrict__ W11, const void* __restrict__ b11,
    const void* __restrict__ W21, const void* __restrict__ b21,
    const void* __restrict__ W12, const void* __restrict__ b12,
    const void* __restrict__ W22, const void* __restrict__ b22,
    const void* __restrict__ Wo,  const void* __restrict__ bo,
    char* __restrict__ ws)
{
  const int isf32 = *(const int*)(ws + WS_FLAG);
  const int blk = blockIdx.x;
  const int tid = threadIdx.x;
  ushort* wt2    = (ushort*)(ws + WS_WT2);
  float*  wot    = (float*)(ws + WS_WOT);
  float*  params = (float*)(ws + WS_PARAMS);
  float*  xf     = (float*)(ws + WS_XF);

  if (blk < 20) {                       // weight fragments
    const int L = blk >> 2, w = blk & 3;
    const void* src = (L == 0) ? W20 : (L == 1) ? W11 : (L == 2) ? W21
                    : (L == 3) ? W12 : W22;
#pragma unroll
    for (int uu = 0; uu < 2; ++uu) {
      const int u = tid + uu * 256;     // 512 units: (n,kk,lane)
      const int n = u >> 8, kk = (u >> 6) & 3, lane = u & 63;
      const int ln = lane & 15, quad = lane >> 4;
      const int col = w * 32 + n * 16 + ln;
      ushort* dst = wt2 + ((((L * 4 + w) * 2 + n) * 4 + kk) * 64 + lane) * 8;
      for (int t = 0; t < 8; ++t) {
        const int k = kk * 32 + quad * 8 + t;
        dst[t] = f2h_bits(dload(src, k * 128 + col, isf32));
      }
    }
  } else if (blk == 20) {               // Wo^T fp32
    for (int idx = tid; idx < 16384; idx += 256) {
      const int o = idx >> 7, k = idx & 127;
      wot[o * 128 + k] = dload(Wo, k * 128 + o, isf32);
    }
  } else {                              // params + x
    if (tid < 128) {
      const void* vecs[8] = {w10, b10, b20, b11, b21, b12, b22, bo};
      for (int v = 0; v < 8; ++v) params[v * 128 + tid] = dload(vecs[v], tid, isf32);
    }
    for (int i = tid; i < 2048; i += 256) xf[i] = dload(x, i, isf32);
  }
}

// ---- GEMM layer: sIn(128x128 f16) x wave's 32-col weight slice ------------
// Verified gfx950 16x16x32 layouts (bf16-family; f16 identical structure):
//   A: lane l holds A[m=l&15][k=(l>>4)*8+t]
//   B: lane l holds B[k=(l>>4)*8+t][n=l&15]
//   C/D: lane l reg r -> row (l>>4)*4+r, col l&15
template<int ACT>
__device__ __forceinline__ void layer_gemm(
    const ushort* sIn, ushort* sOut, const half8 (&bw)[2][4],
    const float brow[2], int ln, int quad, int w)
{
#pragma unroll
  for (int mt = 0; mt < 8; ++mt) {
    half8 aF[4];
#pragma unroll
    for (int kk = 0; kk < 4; ++kk)
      aF[kk] = *(const half8*)(const void*)(sIn + (mt * 16 + ln) * LDP + kk * 32 + quad * 8);
#pragma unroll
    for (int n = 0; n < 2; ++n) {
      floatx4 acc = {0.f, 0.f, 0.f, 0.f};
#pragma unroll
      for (int kk = 0; kk < 4; ++kk)
        acc = __builtin_amdgcn_mfma_f32_16x16x32_f16(aF[kk], bw[n][kk], acc, 0, 0, 0);
#pragma unroll
      for (int r = 0; r < 4; ++r) {
        float v = acc[r] + brow[n];
        if (ACT) v = silu_f(v);
        sOut[(mt * 16 + quad * 4 + r) * LDP + w * 32 + n * 16 + ln] = f2h_bits(v);
      }
    }
  }
}

// last layer: no store, accumulate column partial sums (bias excluded)
__device__ __forceinline__ void layer_reduce(
    const ushort* sIn, const half8 (&bw)[2][4], float psum[2],
    int ln, int quad)
{
#pragma unroll
  for (int mt = 0; mt < 8; ++mt) {
    half8 aF[4];
#pragma unroll
    for (int kk = 0; kk < 4; ++kk)
      aF[kk] = *(const half8*)(const void*)(sIn + (mt * 16 + ln) * LDP + kk * 32 + quad * 8);
#pragma unroll
    for (int n = 0; n < 2; ++n) {
      floatx4 acc = {0.f, 0.f, 0.f, 0.f};
#pragma unroll
      for (int kk = 0; kk < 4; ++kk)
        acc = __builtin_amdgcn_mfma_f32_16x16x32_f16(aF[kk], bw[n][kk], acc, 0, 0, 0);
      psum[n] += acc[0] + acc[1] + acc[2] + acc[3];
    }
  }
}

// ---- kernel 2: fused encoder ----------------------------------------------
__global__ __launch_bounds__(256, 2) void fused2(
    const char* __restrict__ ws, void* __restrict__ out)
{
  __shared__ __align__(16) ushort sA[128 * LDP];
  __shared__ __align__(16) ushort sB[128 * LDP];
  __shared__ float sw10[128], sb10[128];
  __shared__ float colsum[128];
  __shared__ float dists[128];   // reused as mean[] in epilogue

  const int tid  = threadIdx.x;
  const int w    = tid >> 6;       // wave 0..3, owns cols 32w..32w+31
  const int lane = tid & 63;
  const int ln   = lane & 15;
  const int quad = lane >> 4;

  const int b = blockIdx.x >> 9;
  const int i = blockIdx.x & 511;

  const int isf32      = *(const int*)(ws + WS_FLAG);
  const ushort* wt2    = (const ushort*)(ws + WS_WT2);
  const float*  wot    = (const float*)(ws + WS_WOT);
  const float*  params = (const float*)(ws + WS_PARAMS);
  const float*  xf     = (const float*)(ws + WS_XF);

  // weights -> VGPRs, once per block (coalesced 16B/lane)
  half8 bW[5][2][4];
#pragma unroll
  for (int L = 0; L < 5; ++L)
#pragma unroll
    for (int n = 0; n < 2; ++n)
#pragma unroll
      for (int kk = 0; kk < 4; ++kk)
        bW[L][n][kk] = *(const half8*)(const void*)
            (wt2 + ((((L * 4 + w) * 2 + n) * 4 + kk) * 64 + lane) * 8);

  // biases for this lane's two cols, layers 0..3 (b20,b11,b21,b12)
  float brow[4][2];
#pragma unroll
  for (int L = 0; L < 4; ++L)
#pragma unroll
    for (int n = 0; n < 2; ++n)
      brow[L][n] = params[(2 + L) * 128 + w * 32 + n * 16 + ln];

  if (tid < 128) {
    sw10[tid]   = params[0 * 128 + tid];
    sb10[tid]   = params[1 * 128 + tid];
    colsum[tid] = 0.f;
  }
  const float xi0 = xf[(b * 512 + i) * 2 + 0];
  const float xi1 = xf[(b * 512 + i) * 2 + 1];

  float psum[2] = {0.f, 0.f};
  __syncthreads();

  for (int chunk = 0; chunk < 4; ++chunk) {
    if (tid < 128) {
      const int j = chunk * 128 + tid;
      const float dx = xi0 - xf[(b * 512 + j) * 2 + 0];
      const float dy = xi1 - xf[(b * 512 + j) * 2 + 1];
      dists[tid] = sqrtf(dx * dx + dy * dy);
    }
    __syncthreads();   // dists ready; also orders prev-chunk L4 reads vs sA writes

    // layer 0: a0[jj][c] = silu(d*w10[c]+b10[c]) -> sA. Thread: row tid>>1,
    // 64-col half tid&1, short4v packed stores.
    {
      const int row = tid >> 1, c0 = (tid & 1) * 64;
      const float d = dists[row];
      ushort* dst = sA + row * LDP + c0;
#pragma unroll
      for (int c = 0; c < 64; c += 4) {
        short4v pk;
#pragma unroll
        for (int q = 0; q < 4; ++q)
          pk[q] = (short)f2h_bits(silu_f(d * sw10[c0 + c + q] + sb10[c0 + c + q]));
        *(short4v*)(void*)(dst + c) = pk;
      }
    }
    __syncthreads();

    layer_gemm<0>(sA, sB, bW[0], brow[0], ln, quad, w);  // h1 = a0@W20+b20
    __syncthreads();
    layer_gemm<1>(sB, sA, bW[1], brow[1], ln, quad, w);  // a1 = silu(h1@W11+b11)
    __syncthreads();
    layer_gemm<0>(sA, sB, bW[2], brow[2], ln, quad, w);  // h2 = a1@W21+b21
    __syncthreads();
    layer_gemm<1>(sB, sA, bW[3], brow[3], ln, quad, w);  // a2 = silu(h2@W12+b12)
    __syncthreads();
    layer_reduce(sA, bW[4], psum, ln, quad);             // h3 partial colsums
  }

  // fold per-lane partials (4 quads per col) into colsum
#pragma unroll
  for (int n = 0; n < 2; ++n)
    atomicAdd(&colsum[w * 32 + n * 16 + ln], psum[n]);
  __syncthreads();

  // mean[c] = colsum[c]/512 + b22[c]
  if (tid < 128) dists[tid] = colsum[tid] * (1.0f / 512.0f) + params[6 * 128 + tid];
  __syncthreads();

  // out[b,i,o] = mean . Wo[:,o] + bo[o]
  if (tid < 128) {
    const int o = tid;
    float s = params[7 * 128 + o];
    const float4* wrow = (const float4*)(const void*)(wot + o * 128);
#pragma unroll 4
    for (int k4 = 0; k4 < 32; ++k4) {
      const float4 wv = wrow[k4];
      s += dists[k4 * 4 + 0] * wv.x + dists[k4 * 4 + 1] * wv.y
         + dists[k4 * 4 + 2] * wv.z + dists[k4 * 4 + 3] * wv.w;
    }
    const int idx = (b * 512 + i) * 128 + o;
    if (isf32) ((float*)out)[idx] = s;
    else       ((ushort*)out)[idx] = f2bf(s);
  }
}

// ---- fallback (ws too small): fp32-direct, gathered bf16 weights ----------
template<bool ACT>
__device__ __forceinline__ void gemm_tile_g(
    const ushort* sIn, ushort* sOut, const float* __restrict__ W,
    const float* bias, int wave, int ln, int quad)
{
  typedef __attribute__((ext_vector_type(8))) short short8;
  const int row0 = wave * 32;
  short8 aF[2][4];
#pragma unroll
  for (int mt = 0; mt < 2; ++mt)
#pragma unroll
    for (int kk = 0; kk < 4; ++kk)
      aF[mt][kk] = *(const short8*)(const void*)(sIn + (row0 + mt * 16 + ln) * LDP + kk * 32 + quad * 8);
#pragma unroll
  for (int nt = 0; nt < 8; ++nt) {
    const int col = nt * 16 + ln;
    floatx4 acc0 = {0.f, 0.f, 0.f, 0.f};
    floatx4 acc1 = {0.f, 0.f, 0.f, 0.f};
#pragma unroll
    for (int kk = 0; kk < 4; ++kk) {
      short8 bF;
#pragma unroll
      for (int t = 0; t < 8; ++t)
        bF[t] = (short)f2bf(W[(kk * 32 + quad * 8 + t) * 128 + col]);
      acc0 = __builtin_amdgcn_mfma_f32_16x16x32_bf16(aF[0][kk], bF, acc0, 0, 0, 0);
      acc1 = __builtin_amdgcn_mfma_f32_16x16x32_bf16(aF[1][kk], bF, acc1, 0, 0, 0);
    }
    const float bv = bias[col];
#pragma unroll
    for (int r = 0; r < 4; ++r) {
      float v0 = acc0[r] + bv;
      float v1 = acc1[r] + bv;
      if (ACT) { v0 = silu_f(v0); v1 = silu_f(v1); }
      sOut[(row0 + quad * 4 + r) * LDP + col] = f2bf(v0);
      sOut[(row0 + 16 + quad * 4 + r) * LDP + col] = f2bf(v1);
    }
  }
}

__global__ __launch_bounds__(256, 2) void fused_direct(
    const float* __restrict__ x,
    const float* __restrict__ w10, const float* __restrict__ b10,
    const float* __restrict__ W20, const float* __restrict__ b20,
    const float* __restrict__ W11, const float* __restrict__ b11,
    const float* __restrict__ W21, const float* __restrict__ b21,
    const float* __restrict__ W12, const float* __restrict__ b12,
    const float* __restrict__ W22, const float* __restrict__ b22,
    const float* __restrict__ Wo,  const float* __restrict__ bo,
    float* __restrict__ out)
{
  __shared__ __align__(16) ushort sA[128 * LDP];
  __shared__ __align__(16) ushort sB[128 * LDP];
  __shared__ float sw10[128], sb10[128];
  __shared__ float sbias[5][128];
  __shared__ float colsum[128];
  __shared__ float dists[128];

  const int tid  = threadIdx.x;
  const int wave = tid >> 6;
  const int ln   = tid & 15;
  const int quad = (tid & 63) >> 4;
  const int b = blockIdx.x >> 9;
  const int i = blockIdx.x & 511;

  if (tid < 128) {
    sw10[tid] = w10[tid]; sb10[tid] = b10[tid];
    sbias[0][tid] = b20[tid]; sbias[1][tid] = b11[tid];
    sbias[2][tid] = b21[tid]; sbias[3][tid] = b12[tid];
    sbias[4][tid] = b22[tid]; colsum[tid] = 0.f;
  }
  const float xi0 = x[(b * 512 + i) * 2 + 0];
  const float xi1 = x[(b * 512 + i) * 2 + 1];
  __syncthreads();

  for (int chunk = 0; chunk < 4; ++chunk) {
    if (tid < 128) {
      const int j = chunk * 128 + tid;
      const float dx = xi0 - x[(b * 512 + j) * 2 + 0];
      const float dy = xi1 - x[(b * 512 + j) * 2 + 1];
      dists[tid] = sqrtf(dx * dx + dy * dy);
    }
    __syncthreads();
    for (int e = tid; e < 128 * 128; e += 256) {
      const int jj = e >> 7, c = e & 127;
      sA[jj * LDP + c] = f2bf(silu_f(dists[jj] * sw10[c] + sb10[c]));
    }
    __syncthreads();
    gemm_tile_g<false>(sA, sB, W20, sbias[0], wave, ln, quad);
    __syncthreads();
    gemm_tile_g<true >(sB, sA, W11, sbias[1], wave, ln, quad);
    __syncthreads();
    gemm_tile_g<false>(sA, sB, W21, sbias[2], wave, ln, quad);
    __syncthreads();
    gemm_tile_g<true >(sB, sA, W12, sbias[3], wave, ln, quad);
    __syncthreads();
    gemm_tile_g<false>(sB, sB, W22, sbias[4], wave, ln, quad);
    __syncthreads();
    if (tid < 128) {
      float s = 0.f;
      for (int jj = 0; jj < 128; ++jj) s += bf2f(sB[jj * LDP + tid]);
      atomicAdd(&colsum[tid], s);
    }
    __syncthreads();
  }

  if (tid < 128) {
    const int o = tid;
    float s = bo[o];
    for (int k = 0; k < 128; ++k) s += (colsum[k] * (1.0f / 512.0f)) * Wo[k * 128 + o];
    out[(b * 512 + i) * 128 + o] = s;
  }
}

extern "C" void kernel_launch(void* const* d_in, const int* in_sizes, int n_in,
                              void* d_out, int out_size, void* d_ws, size_t ws_size,
                              hipStream_t stream) {
  (void)in_sizes; (void)n_in; (void)out_size;
  if (ws_size >= (size_t)WS_NEED) {
    sniff_dtype<<<1, 64, 0, stream>>>((const ushort*)d_in[0], (int*)d_ws);
    prep_kernel<<<22, 256, 0, stream>>>(
        d_in[0], d_in[1], d_in[2], d_in[3], d_in[4], d_in[5], d_in[6],
        d_in[7], d_in[8], d_in[9], d_in[10], d_in[11], d_in[12], d_in[13],
        d_in[14], (char*)d_ws);
    fused2<<<1024, 256, 0, stream>>>((const char*)d_ws, d_out);
  } else {
    fused_direct<<<1024, 256, 0, stream>>>(
        (const float*)d_in[0], (const float*)d_in[1], (const float*)d_in[2],
        (const float*)d_in[3], (const float*)d_in[4], (const float*)d_in[5],
        (const float*)d_in[6], (const float*)d_in[7], (const float*)d_in[8],
        (const float*)d_in[9], (const float*)d_in[10], (const float*)d_in[11],
        (const float*)d_in[12], (const float*)d_in[13], (const float*)d_in[14],
        (float*)d_out);
  }
}